// Round 2
// baseline (82.913 us; speedup 1.0000x reference)
//
#include <hip/hip_runtime.h>

// OrdFilter: 5x5 reflect-pad window, mean of top-9. In/out fp32 (16,1,512,512).
//
// Column-sharing sorting-network scheme:
//   - each thread computes 4 consecutive output pixels in x (one strip)
//   - the 8 vertical 5-columns covering the strip are sorted once (10 CE each)
//   - adjacent column pairs merged to sorted-10 via inf-elided bitonic merge
//     (15 CE, verified)
//   - per pixel: top-9 of (pairA ∪ pairB) via bitonic max-trick (9 maxes,
//     valley-shaped) + valley sort (13 CE), then fold the leftover sorted
//     5-column with the (9,5) top-9 max-trick (5 maxes) and sum.
// ~57 compare-exchanges/pixel vs 180 for brute-force chain insertion.
// All arrays constant-indexed & fully unrolled -> VGPRs, no scratch.

#define H 512
#define W 512
#define BY 16            // output rows per block
#define TXD 16           // threads in x
#define SPX 4            // pixels per thread (x strip)
#define BW (TXD * SPX)   // 64 output cols per block
#define PAD 2
#define TILW (BW + 2 * PAD)  // 68
#define TILH (BY + 2 * PAD)  // 20

__device__ __forceinline__ void ce(float& a, float& b) {
    const float lo = fminf(a, b);
    const float hi = fmaxf(a, b);
    a = lo;
    b = hi;
}

// ascending insertion-sort network for 5 (10 CE)
__device__ __forceinline__ void sort5(float& a0, float& a1, float& a2, float& a3, float& a4) {
    ce(a0, a1);
    ce(a1, a2); ce(a0, a1);
    ce(a2, a3); ce(a1, a2); ce(a0, a1);
    ce(a3, a4); ce(a2, a3); ce(a1, a2); ce(a0, a1);
}

// merge two ascending 5-seqs -> ascending S[10].
// = bitonic merge-16 of [A0..A4, +inf x6, B4..B0] with known-inf CEs elided.
__device__ __forceinline__ void merge55(const float A[5], const float B[5], float S[10]) {
    float t0 = A[3], u0 = B[4]; ce(t0, u0);
    float t1 = A[4], u1 = B[3]; ce(t1, u1);
    float L0 = A[0], L1 = A[1], L2 = A[2], L3 = t0, L4 = t1, L5 = B[2], L6 = B[1], L7 = B[0];
    // bitonic merge-8 on the (bitonic) low half
    ce(L0, L4); ce(L1, L5); ce(L2, L6); ce(L3, L7);
    ce(L0, L2); ce(L1, L3); ce(L4, L6); ce(L5, L7);
    ce(L0, L1); ce(L2, L3); ce(L4, L5); ce(L6, L7);
    ce(u0, u1);  // top two
    S[0] = L0; S[1] = L1; S[2] = L2; S[3] = L3;
    S[4] = L4; S[5] = L5; S[6] = L6; S[7] = L7;
    S[8] = u0; S[9] = u1;
}

// sorted (ascending) top-9 of two ascending 10-seqs.
// max-trick gives the top-9 multiset as a valley sequence; CE(0,8) + bitonic
// merge-8 sorts it.
__device__ __forceinline__ void top9_sorted(const float A[10], const float B[10], float S[9]) {
    float d0 = fmaxf(A[1], B[9]);
    float d1 = fmaxf(A[2], B[8]);
    float d2 = fmaxf(A[3], B[7]);
    float d3 = fmaxf(A[4], B[6]);
    float d4 = fmaxf(A[5], B[5]);
    float d5 = fmaxf(A[6], B[4]);
    float d6 = fmaxf(A[7], B[3]);
    float d7 = fmaxf(A[8], B[2]);
    float d8 = fmaxf(A[9], B[1]);
    ce(d0, d8);  // d8 = overall max; d0..d7 bitonic
    ce(d0, d4); ce(d1, d5); ce(d2, d6); ce(d3, d7);
    ce(d0, d2); ce(d1, d3); ce(d4, d6); ce(d5, d7);
    ce(d0, d1); ce(d2, d3); ce(d4, d5); ce(d6, d7);
    S[0] = d0; S[1] = d1; S[2] = d2; S[3] = d3;
    S[4] = d4; S[5] = d5; S[6] = d6; S[7] = d7; S[8] = d8;
}

// mean of top-9 of (S[9] ascending ∪ C[5] ascending) via the (9,5,k=9) max-trick
__device__ __forceinline__ float final_mean(const float S[9], const float C[5]) {
    const float s = fmaxf(S[0], C[4]) + fmaxf(S[1], C[3]) + fmaxf(S[2], C[2]) +
                    fmaxf(S[3], C[1]) + fmaxf(S[4], C[0]) + S[5] + S[6] + S[7] + S[8];
    return s * (1.0f / 9.0f);
}

__global__ __launch_bounds__(256) void ordfilter_kernel(
    const float* __restrict__ in, float* __restrict__ out) {
    __shared__ float tile[TILH * TILW];

    const int bx = blockIdx.x * BW;
    const int by = blockIdx.y * BY;
    const int b  = blockIdx.z;
    const float* __restrict__ src = in  + (size_t)b * H * W;
    float* __restrict__ dst       = out + (size_t)b * H * W;

    const int tx  = threadIdx.x;
    const int ty  = threadIdx.y;
    const int tid = ty * TXD + tx;

    // ---- stage reflect-padded tile (20x68) ----
    #pragma unroll
    for (int idx = tid; idx < TILH * TILW; idx += 256) {
        const int ly = idx / TILW;
        const int lx = idx % TILW;
        int gy = by + ly - PAD;
        int gx = bx + lx - PAD;
        gy = gy < 0 ? -gy : (gy >= H ? 2 * H - 2 - gy : gy);
        gx = gx < 0 ? -gx : (gx >= W ? 2 * W - 2 - gx : gx);
        tile[idx] = src[gy * W + gx];
    }
    __syncthreads();

    // ---- load 8 columns (5 rows) via aligned float4 LDS reads ----
    float col[8][5];
    #pragma unroll
    for (int i = 0; i < 5; ++i) {
        const float4 a = *reinterpret_cast<const float4*>(&tile[(ty + i) * TILW + tx * SPX]);
        const float4 c = *reinterpret_cast<const float4*>(&tile[(ty + i) * TILW + tx * SPX + 4]);
        col[0][i] = a.x; col[1][i] = a.y; col[2][i] = a.z; col[3][i] = a.w;
        col[4][i] = c.x; col[5][i] = c.y; col[6][i] = c.z; col[7][i] = c.w;
    }

    // ---- sort the 8 shared columns ----
    #pragma unroll
    for (int k = 0; k < 8; ++k) {
        sort5(col[k][0], col[k][1], col[k][2], col[k][3], col[k][4]);
    }

    // ---- pair merges -> sorted-10s ----
    float E0[10], E1[10], E2[10], E3[10];
    merge55(col[0], col[1], E0);
    merge55(col[2], col[3], E1);
    merge55(col[4], col[5], E2);
    merge55(col[6], col[7], E3);

    // ---- per-pixel top-9 (pix1 & pix2 share D12) ----
    float D01[9], D12[9], D23[9];
    top9_sorted(E0, E1, D01);
    top9_sorted(E1, E2, D12);
    top9_sorted(E2, E3, D23);

    float4 res;
    res.x = final_mean(D01, col[4]);  // cols 0-4, single = col 4
    res.y = final_mean(D12, col[1]);  // cols 1-5, single = col 1
    res.z = final_mean(D12, col[6]);  // cols 2-6, single = col 6
    res.w = final_mean(D23, col[3]);  // cols 3-7, single = col 3

    *reinterpret_cast<float4*>(&dst[(by + ty) * W + bx + tx * SPX]) = res;
}

extern "C" void kernel_launch(void* const* d_in, const int* in_sizes, int n_in,
                              void* d_out, int out_size, void* d_ws, size_t ws_size,
                              hipStream_t stream) {
    const float* in = (const float*)d_in[0];
    float* out      = (float*)d_out;
    dim3 grid(W / BW, H / BY, 16);  // 8 x 32 x 16
    dim3 block(TXD, BY);            // 256 threads
    ordfilter_kernel<<<grid, block, 0, stream>>>(in, out);
}